// Round 8
// baseline (3371.674 us; speedup 1.0000x reference)
//
#include <hip/hip_runtime.h>

#define NB 2
#define NS 4096
#define NH 16
#define NKV 8
#define ND 128
#define NM 256
#define NCNK 32

#define SCALE_A 0.29730177875068026f   // 128^-0.25
#define PHI_SCALE 0.0625f              // 256^-0.5
#define EPSF 1e-6f

typedef unsigned short u16;
typedef unsigned int u32;
typedef unsigned char u8;

// ---- bf16 <-> fp32 helpers --------------------------------------------------
static __device__ __forceinline__ float bfh(u16 v) {
  return __uint_as_float(((u32)v) << 16);
}
static __device__ __forceinline__ u32 f2bf1(float f) {
  u32 u = __float_as_uint(f);
  return (u + 0x7fffu + ((u >> 16) & 1u)) >> 16;
}
static __device__ __forceinline__ u32 pack2(float a, float b) {
  return f2bf1(a) | (f2bf1(b) << 16);
}
static __device__ __forceinline__ void unp8(uint4 p, float* f) {
  f[0] = __uint_as_float(p.x << 16); f[1] = __uint_as_float(p.x & 0xffff0000u);
  f[2] = __uint_as_float(p.y << 16); f[3] = __uint_as_float(p.y & 0xffff0000u);
  f[4] = __uint_as_float(p.z << 16); f[5] = __uint_as_float(p.z & 0xffff0000u);
  f[6] = __uint_as_float(p.w << 16); f[7] = __uint_as_float(p.w & 0xffff0000u);
}
static __device__ __forceinline__ void ld8(const u16* p, float* f) {
  unp8(*(const uint4*)p, f);
}
static __device__ __forceinline__ void ld8(const float* p, float* f) {
  const float4 a = *(const float4*)p;
  const float4 b = *(const float4*)(p + 4);
  f[0]=a.x; f[1]=a.y; f[2]=a.z; f[3]=a.w;
  f[4]=b.x; f[5]=b.y; f[6]=b.z; f[7]=b.w;
}
// store 8 consecutive values from fp32 regs into bf16 or fp32 memory
static __device__ __forceinline__ void st8(u16* p, const float* o) {
  uint4 w;
  w.x = pack2(o[0], o[1]); w.y = pack2(o[2], o[3]);
  w.z = pack2(o[4], o[5]); w.w = pack2(o[6], o[7]);
  *(uint4*)p = w;
}
static __device__ __forceinline__ void st8(float* p, const float* o) {
  *(float4*)(p + 0) = make_float4(o[0], o[1], o[2], o[3]);
  *(float4*)(p + 4) = make_float4(o[4], o[5], o[6], o[7]);
}

static __device__ __forceinline__ unsigned f2key(float f) {
  unsigned u = __float_as_uint(f);
  return (u & 0x80000000u) ? ~u : (u | 0x80000000u);
}
static __device__ __forceinline__ float key2f(unsigned k) {
  return (k & 0x80000000u) ? __uint_as_float(k & 0x7fffffffu) : __uint_as_float(~k);
}

__global__ void fill_out_f32(float* __restrict__ out, float val)
{
  const size_t idx = (size_t)blockIdx.x * 256 + threadIdx.x;
  out[idx] = val;
}

// ---------------------------------------------------------------------------
// NT GEMM, templated in/out dtypes, fp32 accumulate:
//   C[N,Nc] = A[N,K] @ B[Nc,K]^T
// 128x128 tile / 256 threads / 8x8 per thread / K-tiles of 16.
// ---------------------------------------------------------------------------
template <class TA, class TB, class TO>
__global__ __launch_bounds__(256) void gemm_nt(
    const TA* __restrict__ A, const TB* __restrict__ Bm,
    TO* __restrict__ C, int K, int Nc)
{
  __shared__ float At[16][132];
  __shared__ float Bt[16][132];
  const int t  = threadIdx.x;
  const int tx = t & 15, ty = t >> 4;
  const int rowBase = blockIdx.y * 128;
  const int colBase = blockIdx.x * 128;
  const int lr = t >> 1;
  const int lk = (t & 1) * 8;
  const TA* Ag = A  + (size_t)(rowBase + lr) * K + lk;
  const TB* Bg = Bm + (size_t)(colBase + lr) * K + lk;

  float acc[8][8];
#pragma unroll
  for (int i = 0; i < 8; ++i)
#pragma unroll
    for (int j = 0; j < 8; ++j) acc[i][j] = 0.f;

  for (int k0 = 0; k0 < K; k0 += 16) {
    float af[8], bf_[8];
    ld8(Ag + k0, af);
    ld8(Bg + k0, bf_);
    __syncthreads();
#pragma unroll
    for (int j = 0; j < 8; ++j) { At[lk+j][lr] = af[j]; Bt[lk+j][lr] = bf_[j]; }
    __syncthreads();
#pragma unroll
    for (int kk = 0; kk < 16; ++kk) {
      float av[8], bv[8];
      *(float4*)&av[0] = *(const float4*)&At[kk][ty*8];
      *(float4*)&av[4] = *(const float4*)&At[kk][ty*8+4];
      *(float4*)&bv[0] = *(const float4*)&Bt[kk][tx*8];
      *(float4*)&bv[4] = *(const float4*)&Bt[kk][tx*8+4];
#pragma unroll
      for (int i = 0; i < 8; ++i)
#pragma unroll
        for (int j = 0; j < 8; ++j) acc[i][j] += av[i]*bv[j];
    }
  }
#pragma unroll
  for (int i = 0; i < 8; ++i) {
    TO* crow = C + (size_t)(rowBase + ty*8 + i) * Nc + colBase + tx*8;
    st8(crow, acc[i]);
  }
}

// ---------------------------------------------------------------------------
// RoPE in place on bf16 x (B*S, nheads, D); cos/sin fp32 (B,S,D).
// ---------------------------------------------------------------------------
__global__ void rope_bf(u16* __restrict__ x, const float* __restrict__ cosb,
                        const float* __restrict__ sinb, int nheads)
{
  const size_t idx = (size_t)blockIdx.x * blockDim.x + threadIdx.x;
  const int d = (int)(idx & 63);
  const size_t nh = idx >> 6;
  const int h = (int)(nh % nheads);
  const size_t n = nh / nheads;
  const float c1 = cosb[n * ND + d];
  const float s1 = sinb[n * ND + d];
  const float c2 = cosb[n * ND + d + 64];
  const float s2 = sinb[n * ND + d + 64];
  u16* p = x + (n * (size_t)nheads + h) * ND + d;
  const float x1 = bfh(p[0]);
  const float x2 = bfh(p[64]);
  p[0]  = (u16)f2bf1(x1 * c1 - x2 * s1);
  p[64] = (u16)f2bf1(x2 * c2 + x1 * s2);
}

// ---------------------------------------------------------------------------
// Fused feature-map GEMM: U = feature(SCALE_A*X @ P^T), 128 rows/block.
// IS_Q: row-max cancels -sq -> phi = exp(u-rowmax)*PHI_SCALE+EPS.
// !IS_Q: z = u - 0.5*||xn||^2; store exp(z) bf16; atomicMax global max of z.
// ---------------------------------------------------------------------------
template <bool IS_Q>
__global__ __launch_bounds__(256) void feat_gemm(
    const u16* __restrict__ X, const float* __restrict__ P,
    u16* __restrict__ U, unsigned* __restrict__ gmax)
{
  __shared__ float At[16][132];
  __shared__ float Bt[16][260];
  __shared__ float red[128][17];
  __shared__ float rowv[128];
  __shared__ float tmp[256];
  const int t  = threadIdx.x;
  const int tx = t & 15, ty = t >> 4;
  const int rowBase = blockIdx.x * 128;
  const int lr = t >> 1;
  const int lk = (t & 1) * 8;

  float acc[8][16];
#pragma unroll
  for (int i = 0; i < 8; ++i)
#pragma unroll
    for (int j = 0; j < 16; ++j) acc[i][j] = 0.f;
  float sqp = 0.f;

  for (int k0 = 0; k0 < 128; k0 += 16) {
    float af[8], bf0[8], bf1[8];
    ld8(X + (size_t)(rowBase + lr) * 128 + k0 + lk, af);
    ld8(P + (size_t)t * 128 + k0, bf0);
    ld8(P + (size_t)t * 128 + k0 + 8, bf1);
    __syncthreads();
#pragma unroll
    for (int j = 0; j < 8; ++j) {
      const float xs = af[j] * SCALE_A;
      At[lk+j][lr] = xs;
      sqp += xs * xs;
      Bt[j][t]   = bf0[j];
      Bt[8+j][t] = bf1[j];
    }
    __syncthreads();
#pragma unroll
    for (int kk = 0; kk < 16; ++kk) {
      float av[8], bv[16];
      *(float4*)&av[0]  = *(const float4*)&At[kk][ty*8];
      *(float4*)&av[4]  = *(const float4*)&At[kk][ty*8+4];
      *(float4*)&bv[0]  = *(const float4*)&Bt[kk][tx*16];
      *(float4*)&bv[4]  = *(const float4*)&Bt[kk][tx*16+4];
      *(float4*)&bv[8]  = *(const float4*)&Bt[kk][tx*16+8];
      *(float4*)&bv[12] = *(const float4*)&Bt[kk][tx*16+12];
#pragma unroll
      for (int i = 0; i < 8; ++i)
#pragma unroll
        for (int j = 0; j < 16; ++j) acc[i][j] += av[i]*bv[j];
    }
  }

  if (IS_Q) {
#pragma unroll
    for (int i = 0; i < 8; ++i) {
      float rp = -1e30f;
#pragma unroll
      for (int j = 0; j < 16; ++j) rp = fmaxf(rp, acc[i][j]);
      red[ty*8+i][tx] = rp;
    }
    __syncthreads();
    if (t < 128) {
      float mr = red[t][0];
#pragma unroll
      for (int x = 1; x < 16; ++x) mr = fmaxf(mr, red[t][x]);
      rowv[t] = mr;
    }
    __syncthreads();
#pragma unroll
    for (int i = 0; i < 8; ++i) {
      const float mr = rowv[ty*8+i];
      u16* up = U + (size_t)(rowBase + ty*8 + i) * NM + tx*16;
      float o[16];
#pragma unroll
      for (int j = 0; j < 16; ++j) o[j] = expf(acc[i][j] - mr) * PHI_SCALE + EPSF;
      st8(up, o);
      st8(up + 8, o + 8);
    }
  } else {
    tmp[t] = sqp;
    __syncthreads();
    if (t < 128) rowv[t] = 0.5f * (tmp[2*t] + tmp[2*t+1]);
    __syncthreads();
    float lmax = -1e30f;
#pragma unroll
    for (int i = 0; i < 8; ++i) {
      const float sq = rowv[ty*8+i];
#pragma unroll
      for (int j = 0; j < 16; ++j) {
        acc[i][j] -= sq;
        lmax = fmaxf(lmax, acc[i][j]);
      }
    }
    __syncthreads();
    tmp[t] = lmax;
    __syncthreads();
#pragma unroll
    for (int s2 = 128; s2 > 0; s2 >>= 1) {
      if (t < s2) tmp[t] = fmaxf(tmp[t], tmp[t + s2]);
      __syncthreads();
    }
    if (t == 0) atomicMax(gmax, f2key(tmp[0]));
#pragma unroll
    for (int i = 0; i < 8; ++i) {
      u16* up = U + (size_t)(rowBase + ty*8 + i) * NM + tx*16;
      float o[16];
#pragma unroll
      for (int j = 0; j < 16; ++j) o[j] = expf(acc[i][j]);
      st8(up, o);
      st8(up + 8, o + 8);
    }
  }
}

__global__ void init_gmax(unsigned* g) { *g = 0u; }

__global__ void feat_k_b(u16* __restrict__ u, const unsigned* __restrict__ gmax)
{
  const size_t idx = (size_t)blockIdx.x * blockDim.x + threadIdx.x;
  const float eg = expf(-key2f(*gmax));
  const float e = bfh(u[idx]);
  u[idx] = (u16)f2bf1(e * eg * PHI_SCALE + EPSF);
}

// ---------------------------------------------------------------------------
// Per-chunk KV state (bf16 out): KV[bkv][c][m][d], k_sum[bkv][c][m] (fp32).
// ---------------------------------------------------------------------------
__global__ __launch_bounds__(256) void chunk_kv(const u16* __restrict__ phik,
    const u16* __restrict__ v, u16* __restrict__ kvst, float* __restrict__ ksst)
{
  const int dg  = blockIdx.x;     // 0..7
  const int c   = blockIdx.y;     // 0..31
  const int bkv = blockIdx.z;     // b*NKV + kh
  const int b = bkv >> 3, kh = bkv & 7;
  const int t = threadIdx.x;
  __shared__ float Vt[128][20];
  {
    const int i = t >> 1;
    const int dseg = (t & 1) * 8;
    const u16* vp = v + ((size_t)(b*NS + c*128 + i) * NKV + kh) * ND + dg*16 + dseg;
    float vf[8];
    unp8(*(const uint4*)vp, vf);
#pragma unroll
    for (int j = 0; j < 8; ++j) Vt[i][dseg + j] = vf[j];
  }
  __syncthreads();
  const int m = t;
  const size_t pbase = ((size_t)(b*NS + c*128) * NKV + kh) * NM + m;
  const size_t pstr = (size_t)NKV * NM;
  float acc[16];
#pragma unroll
  for (int dl = 0; dl < 16; ++dl) acc[dl] = 0.f;
  float ks = 0.f;
  for (int i = 0; i < 128; ++i) {
    const float pk = bfh(phik[pbase + (size_t)i * pstr]);
    ks += pk;
#pragma unroll
    for (int dl = 0; dl < 16; ++dl) acc[dl] += pk * Vt[i][dl];
  }
  u16* op = kvst + (((size_t)bkv * NCNK + c) * NM + m) * ND + dg*16;
  st8(op, acc);
  st8(op + 8, acc + 8);
  if (dg == 0) ksst[((size_t)bkv * NCNK + c) * NM + m] = ks;
}

// Exclusive prefix over the 32 chunks (in place, bf16 storage, fp32 carry).
__global__ void prefix_kv(u16* __restrict__ kvst)
{
  const int md = blockIdx.x * 256 + threadIdx.x;        // 0..32767
  const size_t base = (size_t)blockIdx.y * NCNK * (NM*ND) + md;
  float carry = 0.f;
  for (int c = 0; c < NCNK; ++c) {
    const size_t a = base + (size_t)c * (NM*ND);
    const float val = bfh(kvst[a]);
    kvst[a] = (u16)f2bf1(carry);
    carry += val;
  }
}

__global__ void prefix_ks(float* __restrict__ ksst)
{
  const int m = threadIdx.x;
  const size_t base = (size_t)blockIdx.x * NCNK * NM + m;
  float carry = 0.f;
  for (int c = 0; c < NCNK; ++c) {
    const size_t a = base + (size_t)c * NM;
    const float val = ksst[a];
    ksst[a] = carry;
    carry += val;
  }
}

// ---------------------------------------------------------------------------
// Per-chunk attention, bf16 in / bf16 out (attn buffer), fp32 math.
// ---------------------------------------------------------------------------
__global__ __launch_bounds__(256) void attn_chunk(
    const u16* __restrict__ phiq, const u16* __restrict__ phik,
    const u16* __restrict__ v, const u16* __restrict__ kvpre,
    const float* __restrict__ kspre, u16* __restrict__ attn)
{
  const int c = blockIdx.x, h = blockIdx.y, b = blockIdx.z;
  const int kh = h >> 1;                 // groups = H/HKV = 2
  const int bkv = b * NKV + kh;
  const int t = threadIdx.x;
  const int tx = t & 15, ty = t >> 4;

  __shared__ float smem[8448];
  __shared__ float rsum[128][17];
  __shared__ float den_l[128];
  __shared__ float s_l[32];

  float (*Pq)[132]  = (float (*)[132])smem;
  float (*Pk)[132]  = (float (*)[132])(smem + 4224);
  float (*Asub)[33] = (float (*)[33])smem;
  float (*Vt2)[132] = (float (*)[132])(smem + 4224);
  float (*St)[132]  = (float (*)[132])(smem + 4224);

  const u16* pqc = phiq + ((size_t)(b*NS + c*128) * NH  + h)  * NM;
  const u16* pkc = phik + ((size_t)(b*NS + c*128) * NKV + kh) * NM;
  const size_t qstr = (size_t)NH * NM;
  const size_t kstr = (size_t)NKV * NM;

  const int lr = t >> 1;
  const int lm = (t & 1) * 16;

  float accA[8][8];
#pragma unroll
  for (int i = 0; i < 8; ++i)
#pragma unroll
    for (int j = 0; j < 8; ++j) accA[i][j] = 0.f;

  // ---- phase A: accA = Pq @ Pk^T
  for (int mt = 0; mt < 8; ++mt) {
    const int m0 = mt * 32;
    const u16* qp = pqc + (size_t)lr * qstr + m0 + lm;
    const u16* kp = pkc + (size_t)lr * kstr + m0 + lm;
    float qf[16], kf[16];
    unp8(*(const uint4*)qp, qf);     unp8(*(const uint4*)(qp+8), qf+8);
    unp8(*(const uint4*)kp, kf);     unp8(*(const uint4*)(kp+8), kf+8);
    __syncthreads();
#pragma unroll
    for (int j = 0; j < 16; ++j) { Pq[lm+j][lr] = qf[j]; Pk[lm+j][lr] = kf[j]; }
    __syncthreads();
    for (int mm = 0; mm < 32; ++mm) {
      float a[8], bb[8];
      *(float4*)&a[0]  = *(const float4*)&Pq[mm][ty*8];
      *(float4*)&a[4]  = *(const float4*)&Pq[mm][ty*8+4];
      *(float4*)&bb[0] = *(const float4*)&Pk[mm][tx*8];
      *(float4*)&bb[4] = *(const float4*)&Pk[mm][tx*8+4];
#pragma unroll
      for (int i = 0; i < 8; ++i)
#pragma unroll
        for (int j = 0; j < 8; ++j) accA[i][j] += a[i]*bb[j];
    }
  }

  // ---- phase B: causal mask + row-sum
#pragma unroll
  for (int ii = 0; ii < 8; ++ii) {
    const int i = ty*8 + ii;
    float rp = 0.f;
#pragma unroll
    for (int jj = 0; jj < 8; ++jj) {
      const int j = tx*8 + jj;
      if (j > i) accA[ii][jj] = 0.f;
      rp += accA[ii][jj];
    }
    rsum[i][tx] = rp;
  }
  __syncthreads();
  if (t < 128) {
    float s = 0.f;
#pragma unroll
    for (int x = 0; x < 16; ++x) s += rsum[t][x];
    den_l[t] = s;
  }

  float acc2[8][8];
#pragma unroll
  for (int i = 0; i < 8; ++i)
#pragma unroll
    for (int j = 0; j < 8; ++j) acc2[i][j] = 0.f;

  // ---- phase C: acc2 += A_masked @ V_chunk
  for (int jb = 0; jb < 4; ++jb) {
    __syncthreads();
    if ((tx >> 2) == jb) {
      const int jloc = (tx & 3) * 8;
#pragma unroll
      for (int ii = 0; ii < 8; ++ii)
#pragma unroll
        for (int jj = 0; jj < 8; ++jj)
          Asub[ty*8+ii][jloc+jj] = accA[ii][jj];
    }
    {
      const int jr = t >> 3;
      const int d0 = (t & 7) * 16;
      const u16* vp = v + ((size_t)(b*NS + c*128 + jb*32 + jr) * NKV + kh) * ND + d0;
      float vf[16];
      unp8(*(const uint4*)vp, vf);   unp8(*(const uint4*)(vp+8), vf+8);
#pragma unroll
      for (int j = 0; j < 16; ++j) Vt2[jr][d0 + j] = vf[j];
    }
    __syncthreads();
    for (int j2 = 0; j2 < 32; ++j2) {
      float a[8], bb[8];
#pragma unroll
      for (int ii = 0; ii < 8; ++ii) a[ii] = Asub[ty*8+ii][j2];
      *(float4*)&bb[0] = *(const float4*)&Vt2[j2][tx*8];
      *(float4*)&bb[4] = *(const float4*)&Vt2[j2][tx*8+4];
#pragma unroll
      for (int ii = 0; ii < 8; ++ii)
#pragma unroll
        for (int jj = 0; jj < 8; ++jj) acc2[ii][jj] += a[ii]*bb[jj];
    }
  }

  // ---- phase D: acc2 += Pq @ S_prefix ; pden = Pq @ s_prefix
  float pden[8];
#pragma unroll
  for (int ii = 0; ii < 8; ++ii) pden[ii] = 0.f;
  for (int mt = 0; mt < 8; ++mt) {
    const int m0 = mt * 32;
    const u16* qp = pqc + (size_t)lr * qstr + m0 + lm;
    float qf[16];
    unp8(*(const uint4*)qp, qf);   unp8(*(const uint4*)(qp+8), qf+8);
    const int mr = t >> 3;
    const int d0 = (t & 7) * 16;
    const u16* sp = kvpre + (((size_t)bkv * NCNK + c) * NM + m0 + mr) * ND + d0;
    float sf[16];
    unp8(*(const uint4*)sp, sf);   unp8(*(const uint4*)(sp+8), sf+8);
    __syncthreads();
#pragma unroll
    for (int j = 0; j < 16; ++j) Pq[lm+j][lr] = qf[j];
#pragma unroll
    for (int j = 0; j < 16; ++j) St[mr][d0 + j] = sf[j];
    if (t < 32) s_l[t] = kspre[((size_t)bkv * NCNK + c) * NM + m0 + t];
    __syncthreads();
    for (int mm = 0; mm < 32; ++mm) {
      float a[8], bb[8];
      *(float4*)&a[0]  = *(const float4*)&Pq[mm][ty*8];
      *(float4*)&a[4]  = *(const float4*)&Pq[mm][ty*8+4];
      *(float4*)&bb[0] = *(const float4*)&St[mm][tx*8];
      *(float4*)&bb[4] = *(const float4*)&St[mm][tx*8+4];
      const float sv = s_l[mm];
#pragma unroll
      for (int ii = 0; ii < 8; ++ii) {
        pden[ii] += a[ii] * sv;
#pragma unroll
        for (int jj = 0; jj < 8; ++jj) acc2[ii][jj] += a[ii]*bb[jj];
      }
    }
  }
  __syncthreads();
  if (tx == 0) {
#pragma unroll
    for (int ii = 0; ii < 8; ++ii) den_l[ty*8+ii] += pden[ii];
  }
  __syncthreads();

  // ---- output bf16 (intermediate attn buffer): num/(den+eps)
#pragma unroll
  for (int ii = 0; ii < 8; ++ii) {
    const int i = ty*8 + ii;
    const float inv = 1.0f / (den_l[i] + EPSF);
    u16* op = attn + ((size_t)(b*NS + c*128 + i) * NH + h) * ND + tx*8;
    float o[8];
#pragma unroll
    for (int jj = 0; jj < 8; ++jj) o[jj] = acc2[ii][jj] * inv;
    st8(op, o);
  }
}

// ---------------------------------------------------------------------------
extern "C" void kernel_launch(void* const* d_in, const int* in_sizes, int n_in,
                              void* d_out, int out_size, void* d_ws, size_t ws_size,
                              hipStream_t stream)
{
  // inputs fp32 (reference dtypes); OUTPUT IS FP32 (reference returns fp32)
  const float* hidden = (const float*)d_in[0];
  const float* cosb   = (const float*)d_in[1];
  const float* sinb   = (const float*)d_in[2];
  const float* wq     = (const float*)d_in[3];
  const float* wk     = (const float*)d_in[4];
  const float* wv     = (const float*)d_in[5];
  const float* wo     = (const float*)d_in[6];
  const float* proj   = (const float*)d_in[7];
  float* out = (float*)d_out;

  const size_t MiB = 1024ull * 1024ull;
  if (ws_size < 146ull * MiB) {         // guard (certified >=192 MiB in R6)
    fill_out_f32<<<65536, 256, 0, stream>>>(out, 400.f);
    return;
  }

  // workspace (~145 MiB): q(32M) | kv(16M) | phiq(64M) | kvst(32M) | ksst | gmax
  u16* q    = (u16*)d_ws;                 // 16777216 bf16 (reused as attn)
  u16* kv   = q    + 16777216;            //  8388608 bf16 (k, then v)
  u16* phiq = kv   +  8388608;            // 33554432 bf16
  u16* kvst = phiq + 33554432;            // 16777216 bf16
  float* ksst = (float*)(kvst + 16777216);//   131072 f32
  unsigned* gmax = (unsigned*)(ksst + 131072);
  u16* phik = (u16*)d_out;                // 16777216 bf16 in d_out's 64 MB;
                                          // dead before final GEMM overwrites
  u16* attn = q;

  // 1) q,k projections (fp32 x fp32 -> bf16)
  gemm_nt<float,float,u16><<<dim3(16,64), 256, 0, stream>>>(hidden, wq, q, 2048, 2048);
  gemm_nt<float,float,u16><<<dim3( 8,64), 256, 0, stream>>>(hidden, wk, kv, 2048, 1024);

  // 2) RoPE in place
  rope_bf<<<32768, 256, 0, stream>>>(q, cosb, sinb, NH);
  rope_bf<<<16384, 256, 0, stream>>>(kv, cosb, sinb, NKV);

  // 3) fused feature-map GEMMs (k first: kv region is reused for v afterwards)
  init_gmax<<<1, 1, 0, stream>>>(gmax);
  feat_gemm<true ><<<1024, 256, 0, stream>>>(q, proj, phiq, gmax);
  feat_gemm<false><<< 512, 256, 0, stream>>>(kv, proj, phik, gmax);
  feat_k_b<<<65536, 256, 0, stream>>>(phik, gmax);

  // 4) v projection into the (now dead) k region
  gemm_nt<float,float,u16><<<dim3( 8,64), 256, 0, stream>>>(hidden, wv, kv, 2048, 1024);

  // 5) chunk states + exclusive prefix over chunks
  chunk_kv<<<dim3(8, NCNK, NB*NKV), 256, 0, stream>>>(phik, kv, kvst, ksst);
  prefix_kv<<<dim3(128, NB*NKV), 256, 0, stream>>>(kvst);
  prefix_ks<<<NB*NKV, 256, 0, stream>>>(ksst);

  // 6) per-chunk causal linear attention (writes attn into q region)
  attn_chunk<<<dim3(NCNK, NH, NB), 256, 0, stream>>>(phiq, phik, kv, kvst, ksst, attn);

  // 7) output projection (bf16 attn x fp32 wo -> FP32 out; overwrites phik)
  gemm_nt<u16,float,float><<<dim3(16,64), 256, 0, stream>>>(attn, wo, out, 2048, 2048);
}